// Round 2
// baseline (296.183 us; speedup 1.0000x reference)
//
#include <hip/hip_runtime.h>

typedef __bf16 bf16_t;
typedef __bf16 bf16x4 __attribute__((ext_vector_type(4)));
typedef __bf16 bf16x8 __attribute__((ext_vector_type(8)));
typedef float floatx4 __attribute__((ext_vector_type(4)));

#define S_H   (8 * 2048 * 256)   // elements per H buffer (4,194,304)

__device__ inline void split_hl(float v, bf16_t& hi, bf16_t& lo) {
    hi = (bf16_t)v;
    lo = (bf16_t)(v - (float)hi);
}

// ---------------- kernel 1: transpose + hi/lo split W (3x 256x256 fp32) ----------------
// Wt[d][c] as bf16 hi + lo
__global__ void wtrans_kernel(const float* __restrict__ W1,
                              const float* __restrict__ W2,
                              const float* __restrict__ W3,
                              bf16_t* __restrict__ Wthi, bf16_t* __restrict__ Wtlo) {
    __shared__ float T[64 * 68];
    const int zi = blockIdx.z;
    const float* W = (zi == 0) ? W1 : ((zi == 1) ? W2 : W3);
    bf16_t* ohi = Wthi + zi * 256 * 256;
    bf16_t* olo = Wtlo + zi * 256 * 256;
    const int c0 = blockIdx.x * 64, d0 = blockIdx.y * 64;
    const int tid = threadIdx.x;
#pragma unroll
    for (int i = 0; i < 4; i++) {   // read 64(c) x 64(d) fp32, coalesced
        int idx = i * 256 + tid;
        int r = idx >> 4, c4 = (idx & 15) * 4;
        floatx4 v = *(const floatx4*)(W + (c0 + r) * 256 + d0 + c4);
        *(floatx4*)(&T[r * 68 + c4]) = v;
    }
    __syncthreads();
#pragma unroll
    for (int i = 0; i < 4; i++) {   // write transposed hi/lo
        int idx = i * 256 + tid;
        int rd = idx & 63, cc4 = (idx >> 6) * 4;
        bf16x4 vh, vl;
#pragma unroll
        for (int ii = 0; ii < 4; ii++) {
            float v = T[(cc4 + ii) * 68 + rd];
            bf16_t h, l; split_hl(v, h, l);
            vh[ii] = h; vl[ii] = l;
        }
        *(bf16x4*)(ohi + (d0 + rd) * 256 + c0 + cc4) = vh;
        *(bf16x4*)(olo + (d0 + rd) * 256 + c0 + cc4) = vl;
    }
}

// ---------------- kernel 2: projections (X fp32, W hi/lo bf16) ----------------
// z=0: H1 = X@W1 -> hi/lo split   z=1: H2 hi/lo   z=2: H3t[b][d][n] bf16 (transposed)
__global__ __launch_bounds__(256) void proj_kernel(
    const float* __restrict__ X,
    const bf16_t* __restrict__ Wthi, const bf16_t* __restrict__ Wtlo,
    bf16_t* __restrict__ H1hi, bf16_t* __restrict__ H1lo,
    bf16_t* __restrict__ H2hi, bf16_t* __restrict__ H2lo,
    bf16_t* __restrict__ H3t) {
    __shared__ bf16_t Xh[64 * 40], Xl[64 * 40];
    __shared__ bf16_t Wh[256 * 40], Wl[256 * 40];
    const int z = blockIdx.y;
    const int row0 = blockIdx.x * 64;
    const int tid = threadIdx.x;
    const int w = tid >> 6, lane = tid & 63;
    const int m = lane & 15, q = lane >> 4;
    const bf16_t* Wzh = Wthi + z * 256 * 256;
    const bf16_t* Wzl = Wtlo + z * 256 * 256;

    floatx4 acc[16];
#pragma unroll
    for (int i = 0; i < 16; i++) acc[i] = (floatx4){0.f, 0.f, 0.f, 0.f};

    for (int c0 = 0; c0 < 256; c0 += 32) {
#pragma unroll
        for (int i = 0; i < 2; i++) {   // stage X chunk 64x32 fp32 -> hi/lo bf16
            int idx = i * 256 + tid;
            int r = idx >> 3, c4 = (idx & 7) * 4;
            floatx4 v = *(const floatx4*)(X + (row0 + r) * 256 + c0 + c4);
            bf16x4 vh, vl;
#pragma unroll
            for (int ii = 0; ii < 4; ii++) {
                bf16_t h, l; split_hl(v[ii], h, l);
                vh[ii] = h; vl[ii] = l;
            }
            *(bf16x4*)(&Xh[r * 40 + c4]) = vh;
            *(bf16x4*)(&Xl[r * 40 + c4]) = vl;
        }
#pragma unroll
        for (int i = 0; i < 4; i++) {   // stage Wt chunk 256x32 hi/lo
            int idx = i * 256 + tid;
            int d = idx >> 2, c8 = (idx & 3) * 8;
            *(bf16x8*)(&Wh[d * 40 + c8]) = *(const bf16x8*)(Wzh + d * 256 + c0 + c8);
            *(bf16x8*)(&Wl[d * 40 + c8]) = *(const bf16x8*)(Wzl + d * 256 + c0 + c8);
        }
        __syncthreads();
        bf16x8 ah = *(const bf16x8*)(&Xh[(w * 16 + m) * 40 + q * 8]);
        bf16x8 al = *(const bf16x8*)(&Xl[(w * 16 + m) * 40 + q * 8]);
#pragma unroll
        for (int nt = 0; nt < 16; nt++) {
            bf16x8 bh = *(const bf16x8*)(&Wh[(nt * 16 + m) * 40 + q * 8]);
            bf16x8 bl = *(const bf16x8*)(&Wl[(nt * 16 + m) * 40 + q * 8]);
            acc[nt] = __builtin_amdgcn_mfma_f32_16x16x32_bf16(ah, bh, acc[nt], 0, 0, 0);
            acc[nt] = __builtin_amdgcn_mfma_f32_16x16x32_bf16(ah, bl, acc[nt], 0, 0, 0);
            acc[nt] = __builtin_amdgcn_mfma_f32_16x16x32_bf16(al, bh, acc[nt], 0, 0, 0);
        }
        __syncthreads();
    }
    const int rbase = row0 + w * 16 + q * 4;   // token row base for C-layout
    if (z < 2) {
        bf16_t* Hhi = (z == 0) ? H1hi : H2hi;
        bf16_t* Hlo = (z == 0) ? H1lo : H2lo;
#pragma unroll
        for (int nt = 0; nt < 16; nt++)
#pragma unroll
            for (int r = 0; r < 4; r++) {
                bf16_t h, l; split_hl(acc[nt][r], h, l);
                int off = (rbase + r) * 256 + nt * 16 + m;
                Hhi[off] = h;
                Hlo[off] = l;
            }
    } else {
#pragma unroll
        for (int nt = 0; nt < 16; nt++)
#pragma unroll
            for (int r = 0; r < 4; r++) {
                int token = rbase + r;
                int b = token >> 11, n = token & 2047;
                H3t[(b * 256 + nt * 16 + m) * 2048 + n] = (bf16_t)acc[nt][r];
            }
    }
}

// ---------------- kernel 3: fused masked attention (flash-style) ----------------
__global__ __launch_bounds__(256) void attn_kernel(
    const bf16_t* __restrict__ H1hi, const bf16_t* __restrict__ H1lo,
    const bf16_t* __restrict__ H2hi, const bf16_t* __restrict__ H2lo,
    const bf16_t* __restrict__ H3t, const int* __restrict__ adj,
    float* __restrict__ out) {
    __shared__ bf16_t Kl[2][32 * 264];   // hi/lo K tile [32 rows][256 +pad]
    __shared__ bf16_t Vl[256 * 40];      // Vt tile [256 d][32 k +pad]
    __shared__ bf16_t Pl[4][16 * 40];    // per-wave P round-trip

    const int b = blockIdx.y;
    const int q0 = blockIdx.x * 64;
    const int tid = threadIdx.x;
    const int w = tid >> 6, lane = tid & 63;
    const int m = lane & 15, q = lane >> 4;

    // Q fragments (A-layout: row = lane&15), hi+lo split, K=256 -> 8 chunks
    const bf16_t* qrh = H1hi + (b * 2048 + q0 + w * 16 + m) * 256;
    const bf16_t* qrl = H1lo + (b * 2048 + q0 + w * 16 + m) * 256;
    bf16x8 qhi[8], qlo[8];
#pragma unroll
    for (int ck = 0; ck < 8; ck++) {
        qhi[ck] = *(const bf16x8*)(qrh + ck * 32 + q * 8);
        qlo[ck] = *(const bf16x8*)(qrl + ck * 32 + q * 8);
    }

    float m_run[4], l_run[4];
#pragma unroll
    for (int r = 0; r < 4; r++) { m_run[r] = -3.0e38f; l_run[r] = 0.f; }
    floatx4 o[16];
#pragma unroll
    for (int i = 0; i < 16; i++) o[i] = (floatx4){0.f, 0.f, 0.f, 0.f};

    const int* adjrow[4];
#pragma unroll
    for (int r = 0; r < 4; r++) adjrow[r] = adj + (q0 + w * 16 + q * 4 + r) * 2048;

    for (int k0 = 0; k0 < 2048; k0 += 32) {
        // ---- stage K hi/lo: 32 x 256 each ----
#pragma unroll
        for (int i = 0; i < 4; i++) {
            int idx = i * 256 + tid;
            int r = idx >> 5, c8 = (idx & 31) * 8;
            *(bf16x8*)(&Kl[0][r * 264 + c8]) =
                *(const bf16x8*)(H2hi + (b * 2048 + k0 + r) * 256 + c8);
            *(bf16x8*)(&Kl[1][r * 264 + c8]) =
                *(const bf16x8*)(H2lo + (b * 2048 + k0 + r) * 256 + c8);
        }
        // ---- stage Vt: 256 d x 32 k ----
#pragma unroll
        for (int i = 0; i < 4; i++) {
            int idx = i * 256 + tid;
            int d = idx >> 2, k8 = (idx & 3) * 8;
            *(bf16x8*)(&Vl[d * 40 + k8]) =
                *(const bf16x8*)(H3t + (b * 256 + d) * 2048 + k0 + k8);
        }
        __syncthreads();

        // ---- S = Q K^T (hi*hi + hi*lo + lo*hi), 16 rows x 32 cols per wave ----
        floatx4 s[2];
#pragma unroll
        for (int t = 0; t < 2; t++) {
            floatx4 accs = (floatx4){0.f, 0.f, 0.f, 0.f};
#pragma unroll
            for (int ck = 0; ck < 8; ck++) {
                bf16x8 khi = *(const bf16x8*)(&Kl[0][(t * 16 + m) * 264 + ck * 32 + q * 8]);
                bf16x8 klo = *(const bf16x8*)(&Kl[1][(t * 16 + m) * 264 + ck * 32 + q * 8]);
                accs = __builtin_amdgcn_mfma_f32_16x16x32_bf16(qhi[ck], khi, accs, 0, 0, 0);
                accs = __builtin_amdgcn_mfma_f32_16x16x32_bf16(qhi[ck], klo, accs, 0, 0, 0);
                accs = __builtin_amdgcn_mfma_f32_16x16x32_bf16(qlo[ck], khi, accs, 0, 0, 0);
            }
            s[t] = accs;
        }

        // ---- leaky-relu + adjacency mask + tile row max ----
        float p[2][4], tmax[4];
#pragma unroll
        for (int r = 0; r < 4; r++) tmax[r] = -3.0e38f;
#pragma unroll
        for (int t = 0; t < 2; t++)
#pragma unroll
            for (int r = 0; r < 4; r++) {
                float v = s[t][r];
                v = (v > 0.f) ? v : 0.2f * v;
                int a = adjrow[r][k0 + t * 16 + m];
                v = (a > 0) ? v : -1.0e12f;
                p[t][r] = v;
                tmax[r] = fmaxf(tmax[r], v);
            }
#pragma unroll
        for (int off = 1; off < 16; off <<= 1)
#pragma unroll
            for (int r = 0; r < 4; r++)
                tmax[r] = fmaxf(tmax[r], __shfl_xor(tmax[r], off, 64));

        // ---- online softmax update ----
        float alpha[4], rsum[4];
#pragma unroll
        for (int r = 0; r < 4; r++) {
            float mnew = fmaxf(m_run[r], tmax[r]);
            alpha[r] = __expf(m_run[r] - mnew);
            m_run[r] = mnew;
            float sum = 0.f;
#pragma unroll
            for (int t = 0; t < 2; t++) {
                float e = __expf(p[t][r] - mnew);
                p[t][r] = e;
                sum += e;
            }
            rsum[r] = sum;
        }
#pragma unroll
        for (int off = 1; off < 16; off <<= 1)
#pragma unroll
            for (int r = 0; r < 4; r++)
                rsum[r] += __shfl_xor(rsum[r], off, 64);
#pragma unroll
        for (int r = 0; r < 4; r++) l_run[r] = l_run[r] * alpha[r] + rsum[r];
#pragma unroll
        for (int nt = 0; nt < 16; nt++)
#pragma unroll
            for (int r = 0; r < 4; r++) o[nt][r] *= alpha[r];

        // ---- P: C-layout -> LDS -> A-layout (per-wave buffer, no barrier) ----
#pragma unroll
        for (int t = 0; t < 2; t++)
#pragma unroll
            for (int r = 0; r < 4; r++)
                Pl[w][(q * 4 + r) * 40 + t * 16 + m] = (bf16_t)p[t][r];
        bf16x8 pf = *(const bf16x8*)(&Pl[w][m * 40 + q * 8]);

        // ---- O += P @ V ----
#pragma unroll
        for (int nt = 0; nt < 16; nt++) {
            bf16x8 vf = *(const bf16x8*)(&Vl[(nt * 16 + m) * 40 + q * 8]);
            o[nt] = __builtin_amdgcn_mfma_f32_16x16x32_bf16(pf, vf, o[nt], 0, 0, 0);
        }
        __syncthreads();
    }

    // ---- epilogue: divide by l, relu, store fp32 ----
#pragma unroll
    for (int nt = 0; nt < 16; nt++)
#pragma unroll
        for (int r = 0; r < 4; r++) {
            float v = o[nt][r] / l_run[r];
            v = fmaxf(v, 0.f);
            out[(b * 2048 + q0 + w * 16 + q * 4 + r) * 256 + nt * 16 + m] = v;
        }
}

extern "C" void kernel_launch(void* const* d_in, const int* in_sizes, int n_in,
                              void* d_out, int out_size, void* d_ws, size_t ws_size,
                              hipStream_t stream) {
    const float* X   = (const float*)d_in[0];   // [8,2048,256] fp32
    const int*   adj = (const int*)d_in[1];     // [2048,2048] int32
    const float* W1  = (const float*)d_in[2];   // [256,256] fp32
    const float* W2  = (const float*)d_in[3];
    const float* W3  = (const float*)d_in[4];
    float* out = (float*)d_out;                 // [8,2048,256] fp32

    char* ws = (char*)d_ws;
    bf16_t* H1hi = (bf16_t*)(ws + (size_t)0 * S_H * 2);
    bf16_t* H1lo = (bf16_t*)(ws + (size_t)1 * S_H * 2);
    bf16_t* H2hi = (bf16_t*)(ws + (size_t)2 * S_H * 2);
    bf16_t* H2lo = (bf16_t*)(ws + (size_t)3 * S_H * 2);
    bf16_t* H3t  = (bf16_t*)(ws + (size_t)4 * S_H * 2);
    bf16_t* Wthi = (bf16_t*)(ws + (size_t)5 * S_H * 2);                  // 3*256*256 bf16
    bf16_t* Wtlo = (bf16_t*)(ws + (size_t)5 * S_H * 2 + 3 * 256 * 256 * 2);

    wtrans_kernel<<<dim3(4, 4, 3), 256, 0, stream>>>(W1, W2, W3, Wthi, Wtlo);
    proj_kernel<<<dim3(256, 3), 256, 0, stream>>>(X, Wthi, Wtlo,
                                                  H1hi, H1lo, H2hi, H2lo, H3t);
    attn_kernel<<<dim3(32, 8), 256, 0, stream>>>(H1hi, H1lo, H2hi, H2lo, H3t, adj, out);
}